// Round 2
// baseline (197.416 us; speedup 1.0000x reference)
//
#include <hip/hip_runtime.h>
#include <hip/hip_fp16.h>
#include <math.h>

#define N_NODES 100000
#define N_EDGES 3200000
#define N_GRAPHS 512
#define D_FEAT 128
#define F_HID 32

#define RPB 128                 // rows per bucket (row >> 7)
#define NB 782                  // ceil(100000/128)
#define CAP 5120                // fixed bucket capacity (mean 4092 -> 16 sigma margin)
#define CHUNK 8192              // edges per multisplit block
#define SBS 1024                // scatter block size
#define NCHUNK ((N_EDGES + CHUNK - 1) / CHUNK)   // 391
#define CTILES 16               // col tiles per row for gather locality (col >> 13)
#define NKEYS (RPB * CTILES)    // 2048 counting-sort keys
#define SPB 64                  // nodes per spmm block (256 threads / 4 lanes)

typedef unsigned u32x4 __attribute__((ext_vector_type(4)));

static __device__ __forceinline__ __half2 u2h2(unsigned u) {
    return *reinterpret_cast<__half2*>(&u);
}

// ---------------- GEMM1: x[N,128] @ W[128,32] -> f16 [N,32] ----------------
__global__ void gemm128x32(const float* __restrict__ x, const float* __restrict__ W,
                           unsigned short* __restrict__ outh, int n_nodes) {
    __shared__ float Ws[128 * 32];
    for (int i = threadIdx.x; i < 128 * 32; i += 256) Ws[i] = W[i];
    __syncthreads();
    const int fg = threadIdx.x & 7;
    const int nl = threadIdx.x >> 3;
    const int node = blockIdx.x * 32 + nl;
    if (node >= n_nodes) return;
    const float4* x4 = (const float4*)(x + (size_t)node * 128);
    const float4* Ws4 = (const float4*)Ws;
    float4 acc = make_float4(0.f, 0.f, 0.f, 0.f);
    for (int kk = 0; kk < 32; ++kk) {
        float4 xv = x4[kk];
        int k = kk * 4;
        float4 w0 = Ws4[(k + 0) * 8 + fg];
        float4 w1 = Ws4[(k + 1) * 8 + fg];
        float4 w2 = Ws4[(k + 2) * 8 + fg];
        float4 w3 = Ws4[(k + 3) * 8 + fg];
        acc.x += xv.x * w0.x + xv.y * w1.x + xv.z * w2.x + xv.w * w3.x;
        acc.y += xv.x * w0.y + xv.y * w1.y + xv.z * w2.y + xv.w * w3.y;
        acc.z += xv.x * w0.z + xv.y * w1.z + xv.z * w2.z + xv.w * w3.z;
        acc.w += xv.x * w0.w + xv.y * w1.w + xv.z * w2.w + xv.w * w3.w;
    }
    __half2 p0 = __floats2half2_rn(acc.x, acc.y);
    __half2 p1 = __floats2half2_rn(acc.z, acc.w);
    uint2 o = make_uint2(*reinterpret_cast<unsigned*>(&p0),
                         *reinterpret_cast<unsigned*>(&p1));
    ((uint2*)(outh + (size_t)node * 32))[fg] = o;
}

// ================= stage 0: cursor init (fixed-capacity buckets) =================
__global__ void init_cursor(int* __restrict__ cursor) {
    int t = blockIdx.x * blockDim.x + threadIdx.x;
    if (t < NB) cursor[t] = t * CAP;
}

// ====== stage 1: bucket multisplit, LDS-staged, hinted bucket lookup ======
__global__ __launch_bounds__(SBS) void bucket_scatter(
        const int* __restrict__ row, const int* __restrict__ col,
        const float* __restrict__ w, int* __restrict__ cursor,
        uint2* __restrict__ rec, int n_edges) {
    __shared__ uint2 srt[CHUNK];            // 64 KB
    __shared__ int hist[NB];
    __shared__ int lofs[NB + 1];
    __shared__ int lbase[NB];
    __shared__ int tsum[SBS];
    __shared__ unsigned short flr[CHUNK / 16];  // 1 KB bucket hints
    const int t = threadIdx.x;
    const int base = blockIdx.x * CHUNK;
    const int count = min(CHUNK, n_edges - base);

    if (t < NB) hist[t] = 0;
    __syncthreads();
    int rloc[CHUNK / SBS];                  // cache row[] between passes
    #pragma unroll
    for (int j = 0; j < CHUNK / SBS; ++j) {
        int i = t + j * SBS;
        int r = -1;
        if (i < count) { r = row[base + i]; atomicAdd(&hist[r >> 7], 1); }
        rloc[j] = r;
    }
    __syncthreads();
    int v = (t < NB) ? hist[t] : 0;
    tsum[t] = v;
    __syncthreads();
    for (int off = 1; off < SBS; off <<= 1) {
        int add = (t >= off) ? tsum[t - off] : 0;
        __syncthreads();
        tsum[t] += add;
        __syncthreads();
    }
    if (t < NB) lofs[t] = tsum[t] - v;
    if (t == SBS - 1) lofs[NB] = tsum[SBS - 1];
    __syncthreads();
    if (t < NB) {
        lbase[t] = v ? atomicAdd(&cursor[t], v) : 0;
        hist[t] = 0;
    }
    for (int q = t; q < CHUNK / 16; q += SBS) {
        int pos = q * 16;
        int lo = 0, hi = NB;
        while (hi - lo > 1) {
            int mid = (lo + hi) >> 1;
            if (lofs[mid] <= pos) lo = mid; else hi = mid;
        }
        flr[q] = (unsigned short)lo;
    }
    __syncthreads();
    #pragma unroll
    for (int j = 0; j < CHUNK / SBS; ++j) {
        int i = t + j * SBS;
        if (i < count) {
            int e = base + i;
            int r = rloc[j];
            int b = r >> 7;
            int pos = lofs[b] + atomicAdd(&hist[b], 1);
            srt[pos] = make_uint2(((unsigned)(r & 127) << 17) | (unsigned)col[e],
                                  __float_as_uint(w[e]));
        }
    }
    __syncthreads();
    for (int i = t; i < count; i += SBS) {
        uint2 vv = srt[i];
        int b = flr[i >> 4];
        while (lofs[b + 1] <= i) ++b;
        rec[lbase[b] + (i - lofs[b])] = vv;
    }
}

// ================= stage 2: compact-base scan over bucket counts =================
__global__ void scan_nb(const int* __restrict__ cursor, int* __restrict__ bbase) {
    __shared__ int s[1024];
    const int t = threadIdx.x;
    int v = (t < NB) ? (cursor[t] - t * CAP) : 0;
    s[t] = v;
    __syncthreads();
    for (int off = 1; off < 1024; off <<= 1) {
        int add = (t >= off) ? s[t - off] : 0;
        __syncthreads();
        s[t] += add;
        __syncthreads();
    }
    if (t < NB) bbase[t] = s[t] - v;
    if (t == NB - 1) bbase[NB] = s[t];
}

// ====== stage 3: per-bucket counting sort by (row_local, col_tile) -> CSR ======
// rec2[i] = (w_f16_no_sign:15) << 17 | col:17; each row's edges col-tile-ordered.
__global__ __launch_bounds__(512) void bucket_sort(
        const int* __restrict__ cursor, const int* __restrict__ bbase,
        const uint2* __restrict__ rec, unsigned* __restrict__ rec2,
        int* __restrict__ row_ptr, int n_nodes) {
    __shared__ unsigned srt[CAP];     // 20 KB
    __shared__ int hist[NKEYS];       // 8 KB
    __shared__ int lofs[NKEYS];       // 8 KB
    __shared__ int tsum[512];         // 2 KB
    const int t = threadIdx.x;
    const int b = blockIdx.x;
    const int sbase = b * CAP;
    const int cnt = cursor[b] - sbase;
    const int gbase = bbase[b];

    for (int i = t; i < NKEYS; i += 512) hist[i] = 0;
    __syncthreads();
    for (int i = t; i < cnt; i += 512) {
        unsigned rx = rec[sbase + i].x;
        int key = (rx >> 17) * CTILES + ((rx & 0x1FFFFu) >> 13);
        atomicAdd(&hist[key], 1);
    }
    __syncthreads();
    int vals[4];
    int s0 = 0;
    const int k4 = t * 4;
    #pragma unroll
    for (int j = 0; j < 4; ++j) { vals[j] = hist[k4 + j]; s0 += vals[j]; }
    tsum[t] = s0;
    __syncthreads();
    for (int off = 1; off < 512; off <<= 1) {
        int add = (t >= off) ? tsum[t - off] : 0;
        __syncthreads();
        tsum[t] += add;
        __syncthreads();
    }
    {
        int run = tsum[t] - s0;
        #pragma unroll
        for (int j = 0; j < 4; ++j) { lofs[k4 + j] = run; run += vals[j]; }
    }
    __syncthreads();
    if (t < RPB) {
        int gr = b * RPB + t;
        if (gr <= n_nodes) row_ptr[gr] = gbase + lofs[t * CTILES];
    }
    for (int i = t; i < NKEYS; i += 512) hist[i] = lofs[i];
    __syncthreads();
    for (int i = t; i < cnt; i += 512) {
        uint2 v = rec[sbase + i];
        int key = (v.x >> 17) * CTILES + ((v.x & 0x1FFFFu) >> 13);
        int pos = atomicAdd(&hist[key], 1);
        float wf = __uint_as_float(v.y);
        __half hw = __float2half_rn(wf);
        unsigned wb = ((unsigned)*reinterpret_cast<unsigned short*>(&hw)) & 0x7FFFu;
        srt[pos] = (wb << 17) | (v.x & 0x1FFFFu);
    }
    __syncthreads();
    for (int i = t; i < cnt; i += 512)
        rec2[gbase + i] = srt[i];
}

// ---- asm helpers: order-pinned global loads + hand-counted waits ----
// All loop-body VMEM is inline asm so vmcnt accounting is exact.
#define GLOAD4(D, OFF, BASE)                                        \
    asm volatile("global_load_dwordx4 %0, %1, %2"                   \
                 : "=v"(D) : "v"(OFF), "s"(BASE) : "memory")

#define VMWAIT(N) do {                                              \
    asm volatile("s_waitcnt vmcnt(" #N ")" ::: "memory");           \
    __builtin_amdgcn_sched_barrier(0); } while (0)

#define CONSUME(G, P) do {                                          \
    unsigned wu_ = (P) >> 17; wu_ |= wu_ << 16;                     \
    __half2 w2_ = u2h2(wu_);                                        \
    a0 = __hfma2(w2_, u2h2((G).x), a0);                             \
    a1 = __hfma2(w2_, u2h2((G).y), a1);                             \
    a2 = __hfma2(w2_, u2h2((G).z), a2);                             \
    a3 = __hfma2(w2_, u2h2((G).w), a3); } while (0)

#define EDGE1 do {                                                  \
    unsigned p0_ = rec2[i];                                         \
    uint4 g0_ = h4[(size_t)(p0_ & 0x1FFFF) * 4 + fl];               \
    unsigned wu_ = p0_ >> 17; wu_ |= wu_ << 16;                     \
    __half2 w2_ = u2h2(wu_);                                        \
    a0 = __hfma2(w2_, u2h2(g0_.x), a0);                             \
    a1 = __hfma2(w2_, u2h2(g0_.y), a1);                             \
    a2 = __hfma2(w2_, u2h2(g0_.z), a2);                             \
    a3 = __hfma2(w2_, u2h2(g0_.w), a3); } while (0)

// ====== fused SPMM: act = ELU(A.h + b); then project @Wn -> f16, or pool. ======
// 4 lanes/node (uint4 = 8 f16 feats each), 64 nodes/block.
// Inner loop: asm-forced 8-deep gather pipeline, counted vmcnt.
__global__ __launch_bounds__(256) void spmm_fused(
        const int* __restrict__ rp, const unsigned* __restrict__ rec2,
        const unsigned short* __restrict__ h_in, const float* __restrict__ bias,
        const float* __restrict__ Wn,          // 32x32 or nullptr (last layer)
        unsigned short* __restrict__ h_out,    // f16 out if Wn != nullptr
        const int* __restrict__ seg,           // used if Wn == nullptr
        float* __restrict__ G,                 // pooled out if Wn == nullptr
        int n_nodes) {
    __shared__ float Ws[32 * 32];
    __shared__ float vt[SPB][33];
    const int t = threadIdx.x;
    if (Wn) for (int i = t; i < 1024; i += 256) Ws[i] = Wn[i];
    const int fl = t & 3;
    const int nl = t >> 2;
    const int node = blockIdx.x * SPB + nl;
    const bool valid = node < n_nodes;
    const int s = valid ? rp[node] : 0;
    const int e = valid ? rp[node + 1] : 0;
    const uint4* h4 = (const uint4*)h_in;     // row = 4 uint4 (32 f16)
    const unsigned foff = (unsigned)fl * 16u; // byte offset within 64B row
    __half2 a0 = u2h2(0), a1 = u2h2(0), a2 = u2h2(0), a3 = u2h2(0);
    int i = s;
    // scalar prologue to 16B alignment of rec2+i (compiler loads; before asm region)
    for (; i < e && (i & 3); ++i) EDGE1;

    if (i + 8 <= e) {
        const int i0 = i;                      // aligned, valid dummy base
        u32x4 PA, PB;
        VMWAIT(0);                             // drain all compiler loads first
        GLOAD4(PA, (unsigned)i * 4u, rec2);
        GLOAD4(PB, (unsigned)i * 4u + 16u, rec2);
        VMWAIT(0);
        while (true) {
            const unsigned p0 = PA.x, p1 = PA.y, p2 = PA.z, p3 = PA.w;
            const unsigned p4 = PB.x, p5 = PB.y, p6 = PB.z, p7 = PB.w;
            u32x4 g0, g1, g2, g3, g4, g5, g6, g7;
            { unsigned o;
              o = ((p0 & 0x1FFFFu) << 6) + foff; GLOAD4(g0, o, h_in);
              o = ((p1 & 0x1FFFFu) << 6) + foff; GLOAD4(g1, o, h_in);
              o = ((p2 & 0x1FFFFu) << 6) + foff; GLOAD4(g2, o, h_in);
              o = ((p3 & 0x1FFFFu) << 6) + foff; GLOAD4(g3, o, h_in);
              o = ((p4 & 0x1FFFFu) << 6) + foff; GLOAD4(g4, o, h_in);
              o = ((p5 & 0x1FFFFu) << 6) + foff; GLOAD4(g5, o, h_in);
              o = ((p6 & 0x1FFFFu) << 6) + foff; GLOAD4(g6, o, h_in);
              o = ((p7 & 0x1FFFFu) << 6) + foff; GLOAD4(g7, o, h_in);
            }
            i += 8;
            // next-batch rec2 (or safe dummy reload to keep vmcnt uniform)
            {
                unsigned nb = (unsigned)((i + 8 <= e) ? i : i0) * 4u;
                GLOAD4(PA, nb, rec2);
                GLOAD4(PB, nb + 16u, rec2);
            }
            // outstanding: g0..g7, PA, PB = 10
            VMWAIT(6);                         // g0..g3 ready
            CONSUME(g0, p0); CONSUME(g1, p1); CONSUME(g2, p2); CONSUME(g3, p3);
            VMWAIT(2);                         // g4..g7 ready
            CONSUME(g4, p4); CONSUME(g5, p5); CONSUME(g6, p6); CONSUME(g7, p7);
            VMWAIT(0);                         // PA/PB ready; counter clean
            if (i + 8 > e) break;
        }
    }
    // scalar tail (asm loads fully drained; compiler loads safe again)
    for (; i < e; ++i) EDGE1;

    // bias + ELU in fp32
    float acc[8];
    acc[0] = __low2float(a0); acc[1] = __high2float(a0);
    acc[2] = __low2float(a1); acc[3] = __high2float(a1);
    acc[4] = __low2float(a2); acc[5] = __high2float(a2);
    acc[6] = __low2float(a3); acc[7] = __high2float(a3);
    float4 bv0 = ((const float4*)bias)[fl * 2];
    float4 bv1 = ((const float4*)bias)[fl * 2 + 1];
    acc[0] += bv0.x; acc[1] += bv0.y; acc[2] += bv0.z; acc[3] += bv0.w;
    acc[4] += bv1.x; acc[5] += bv1.y; acc[6] += bv1.z; acc[7] += bv1.w;
    #pragma unroll
    for (int j = 0; j < 8; ++j)
        acc[j] = acc[j] > 0.f ? acc[j] : (expf(acc[j]) - 1.f);
    // stage act in LDS
    {
        float* vr = &vt[nl][fl * 8];
        #pragma unroll
        for (int j = 0; j < 8; ++j) vr[j] = acc[j];
    }
    __syncthreads();

    if (Wn) {
        // project @ Wn, emit f16
        const float4* Ws4 = (const float4*)Ws;
        const float* vrow = vt[nl];
        float o[8] = {0.f, 0.f, 0.f, 0.f, 0.f, 0.f, 0.f, 0.f};
        #pragma unroll 8
        for (int k = 0; k < 32; ++k) {
            float vk = vrow[k];
            float4 w0 = Ws4[k * 8 + fl * 2];
            float4 w1 = Ws4[k * 8 + fl * 2 + 1];
            o[0] += vk * w0.x; o[1] += vk * w0.y; o[2] += vk * w0.z; o[3] += vk * w0.w;
            o[4] += vk * w1.x; o[5] += vk * w1.y; o[6] += vk * w1.z; o[7] += vk * w1.w;
        }
        if (valid) {
            __half2 q0 = __floats2half2_rn(o[0], o[1]);
            __half2 q1 = __floats2half2_rn(o[2], o[3]);
            __half2 q2 = __floats2half2_rn(o[4], o[5]);
            __half2 q3 = __floats2half2_rn(o[6], o[7]);
            uint4 ob = make_uint4(*reinterpret_cast<unsigned*>(&q0),
                                  *reinterpret_cast<unsigned*>(&q1),
                                  *reinterpret_cast<unsigned*>(&q2),
                                  *reinterpret_cast<unsigned*>(&q3));
            ((uint4*)h_out)[(size_t)node * 4 + fl] = ob;
        }
    } else {
        // pool: 32 feat lanes x 8 subs, run-accumulate sorted seg over 8 nodes each
        const int f = t & 31;
        const int sub = t >> 5;
        float run = 0.f;
        int cur = -1;
        #pragma unroll
        for (int q = 0; q < 8; ++q) {
            int nloc = sub * 8 + q;
            int node2 = blockIdx.x * SPB + nloc;
            if (node2 >= n_nodes) break;
            int sg = seg[node2];
            if (sg != cur) {
                if (cur >= 0) atomicAdd(&G[(size_t)cur * 32 + f], run);
                cur = sg;
                run = 0.f;
            }
            run += vt[nloc][f];
        }
        if (cur >= 0) atomicAdd(&G[(size_t)cur * 32 + f], run);
    }
}

// ================= MLP head =================
__global__ void head_mlp(const float* __restrict__ g,
                         const float* __restrict__ Wd1, const float* __restrict__ bd1,
                         const float* __restrict__ Wd2, const float* __restrict__ bd2,
                         const float* __restrict__ Wd3, const float* __restrict__ bd3,
                         float* __restrict__ out) {
    __shared__ float gr[32];
    __shared__ float s1[64];
    __shared__ float s2[32];
    const int gid = blockIdx.x;
    const int t = threadIdx.x;
    if (t < 32) gr[t] = g[(size_t)gid * 32 + t];
    __syncthreads();
    float a = bd1[t];
    for (int k = 0; k < 32; ++k) a += gr[k] * Wd1[k * 64 + t];
    s1[t] = fmaxf(a, 0.f);
    __syncthreads();
    if (t < 32) {
        float a2 = bd2[t];
        for (int k = 0; k < 64; ++k) a2 += s1[k] * Wd2[k * 32 + t];
        s2[t] = fmaxf(a2, 0.f);
    }
    __syncthreads();
    if (t == 0) {
        float a3 = bd3[0];
        for (int k = 0; k < 32; ++k) a3 += s2[k] * Wd3[k];
        out[gid] = 1.f / (1.f + expf(-a3));
    }
}

extern "C" void kernel_launch(void* const* d_in, const int* in_sizes, int n_in,
                              void* d_out, int out_size, void* d_ws, size_t ws_size,
                              hipStream_t stream) {
    const float* x   = (const float*)d_in[0];
    const int*   ei  = (const int*)d_in[1];
    const float* ew  = (const float*)d_in[2];
    const int*   seg = (const int*)d_in[3];
    const float* W1  = (const float*)d_in[4];
    const float* b1  = (const float*)d_in[5];
    const float* W2  = (const float*)d_in[6];
    const float* b2  = (const float*)d_in[7];
    const float* W3  = (const float*)d_in[8];
    const float* b3  = (const float*)d_in[9];
    const float* Wd1 = (const float*)d_in[10];
    const float* bd1 = (const float*)d_in[11];
    const float* Wd2 = (const float*)d_in[12];
    const float* bd2 = (const float*)d_in[13];
    const float* Wd3 = (const float*)d_in[14];
    const float* bd3 = (const float*)d_in[15];
    float* out = (float*)d_out;

    const int* rowp = ei;
    const int* colp = ei + N_EDGES;

    const size_t NF  = (size_t)N_NODES * F_HID;
    const size_t REC_BYTES = (size_t)NB * CAP * sizeof(uint2);  // 32.03 MB

    // region A: rec (32 MB) during build; hA (6.4) + hB (6.4) f16 overlay after
    char*  wsb     = (char*)d_ws;
    uint2* rec     = (uint2*)wsb;
    unsigned short* hA = (unsigned short*)wsb;                  // f16 [N,32]
    unsigned short* hB = (unsigned short*)(wsb + NF * 2);       // f16 [N,32]
    unsigned* rec2 = (unsigned*)(wsb + REC_BYTES);              // [E] 4 B records
    int*   cursor  = (int*)(rec2 + N_EDGES);                    // [NB]
    int*   bbase   = cursor + NB;                               // [NB+1]
    int*   row_ptr = bbase + NB + 1;                            // [N+1]
    float* G       = (float*)(row_ptr + N_NODES + 1);           // [512,32]

    const int gemm_grid = (N_NODES + 31) / 32;        // 3125
    const int spmm_grid = (N_NODES + SPB - 1) / SPB;  // 1563

    // ---- CSR build (once per call) ----
    init_cursor<<<(NB + 255) / 256, 256, 0, stream>>>(cursor);
    bucket_scatter<<<NCHUNK, SBS, 0, stream>>>(rowp, colp, ew, cursor, rec, N_EDGES);
    scan_nb<<<1, 1024, 0, stream>>>(cursor, bbase);
    bucket_sort<<<NB, 512, 0, stream>>>(cursor, bbase, rec, rec2, row_ptr, N_NODES);
    hipMemsetAsync(G, 0, (size_t)N_GRAPHS * F_HID * sizeof(float), stream);

    // ---- layer 1: project x@W1 -> hA; fused spmm(+b1,ELU) @W2 -> hB ----
    gemm128x32<<<gemm_grid, 256, 0, stream>>>(x, W1, hA, N_NODES);
    spmm_fused<<<spmm_grid, 256, 0, stream>>>(row_ptr, rec2, hA, b1, W2, hB, nullptr, nullptr, N_NODES);

    // ---- layer 2: fused spmm(+b2,ELU) @W3 -> hA ----
    spmm_fused<<<spmm_grid, 256, 0, stream>>>(row_ptr, rec2, hB, b2, W3, hA, nullptr, nullptr, N_NODES);

    // ---- layer 3: fused spmm(+b3,ELU) + pool -> G ----
    spmm_fused<<<spmm_grid, 256, 0, stream>>>(row_ptr, rec2, hA, b3, nullptr, nullptr, seg, G, N_NODES);

    // ---- head ----
    head_mlp<<<N_GRAPHS, 64, 0, stream>>>(G, Wd1, bd1, Wd2, bd2, Wd3, bd3, out);
}

// Round 3
// 182.473 us; speedup vs baseline: 1.0819x; 1.0819x over previous
//
#include <hip/hip_runtime.h>
#include <hip/hip_fp16.h>
#include <math.h>

#define N_NODES 100000
#define N_EDGES 3200000
#define N_GRAPHS 512
#define D_FEAT 128
#define F_HID 32

#define RPB 128                 // rows per bucket (row >> 7)
#define NB 782                  // ceil(100000/128)
#define CAP 5120                // fixed bucket capacity (mean 4092 -> 16 sigma margin)
#define CHUNK 8192              // edges per multisplit block
#define SBS 1024                // scatter block size
#define NCHUNK ((N_EDGES + CHUNK - 1) / CHUNK)   // 391
#define CTILES 16               // col tiles per row for gather locality (col >> 13)
#define NKEYS (RPB * CTILES)    // 2048 counting-sort keys
#define SPB 64                  // nodes per spmm block (256 threads / 4 lanes)
#define PHASES 8                // col-sweep pacing phases (L2 window ~1-2.5 MB)

static __device__ __forceinline__ __half2 u2h2(unsigned u) {
    return *reinterpret_cast<__half2*>(&u);
}

// ---------------- GEMM1: x[N,128] @ W[128,32] -> f16 [N,32] ----------------
__global__ void gemm128x32(const float* __restrict__ x, const float* __restrict__ W,
                           unsigned short* __restrict__ outh, int n_nodes) {
    __shared__ float Ws[128 * 32];
    for (int i = threadIdx.x; i < 128 * 32; i += 256) Ws[i] = W[i];
    __syncthreads();
    const int fg = threadIdx.x & 7;
    const int nl = threadIdx.x >> 3;
    const int node = blockIdx.x * 32 + nl;
    if (node >= n_nodes) return;
    const float4* x4 = (const float4*)(x + (size_t)node * 128);
    const float4* Ws4 = (const float4*)Ws;
    float4 acc = make_float4(0.f, 0.f, 0.f, 0.f);
    for (int kk = 0; kk < 32; ++kk) {
        float4 xv = x4[kk];
        int k = kk * 4;
        float4 w0 = Ws4[(k + 0) * 8 + fg];
        float4 w1 = Ws4[(k + 1) * 8 + fg];
        float4 w2 = Ws4[(k + 2) * 8 + fg];
        float4 w3 = Ws4[(k + 3) * 8 + fg];
        acc.x += xv.x * w0.x + xv.y * w1.x + xv.z * w2.x + xv.w * w3.x;
        acc.y += xv.x * w0.y + xv.y * w1.y + xv.z * w2.y + xv.w * w3.y;
        acc.z += xv.x * w0.z + xv.y * w1.z + xv.z * w2.z + xv.w * w3.z;
        acc.w += xv.x * w0.w + xv.y * w1.w + xv.z * w2.w + xv.w * w3.w;
    }
    __half2 p0 = __floats2half2_rn(acc.x, acc.y);
    __half2 p1 = __floats2half2_rn(acc.z, acc.w);
    uint2 o = make_uint2(*reinterpret_cast<unsigned*>(&p0),
                         *reinterpret_cast<unsigned*>(&p1));
    ((uint2*)(outh + (size_t)node * 32))[fg] = o;
}

// ================= stage 0: cursor init (fixed-capacity buckets) =================
__global__ void init_cursor(int* __restrict__ cursor) {
    int t = blockIdx.x * blockDim.x + threadIdx.x;
    if (t < NB) cursor[t] = t * CAP;
}

// ====== stage 1: bucket multisplit, LDS-staged, hinted bucket lookup ======
__global__ __launch_bounds__(SBS) void bucket_scatter(
        const int* __restrict__ row, const int* __restrict__ col,
        const float* __restrict__ w, int* __restrict__ cursor,
        uint2* __restrict__ rec, int n_edges) {
    __shared__ uint2 srt[CHUNK];            // 64 KB
    __shared__ int hist[NB];
    __shared__ int lofs[NB + 1];
    __shared__ int lbase[NB];
    __shared__ int tsum[SBS];
    __shared__ unsigned short flr[CHUNK / 16];  // 1 KB bucket hints
    const int t = threadIdx.x;
    const int base = blockIdx.x * CHUNK;
    const int count = min(CHUNK, n_edges - base);

    if (t < NB) hist[t] = 0;
    __syncthreads();
    int rloc[CHUNK / SBS];                  // cache row[] between passes
    #pragma unroll
    for (int j = 0; j < CHUNK / SBS; ++j) {
        int i = t + j * SBS;
        int r = -1;
        if (i < count) { r = row[base + i]; atomicAdd(&hist[r >> 7], 1); }
        rloc[j] = r;
    }
    __syncthreads();
    int v = (t < NB) ? hist[t] : 0;
    tsum[t] = v;
    __syncthreads();
    for (int off = 1; off < SBS; off <<= 1) {
        int add = (t >= off) ? tsum[t - off] : 0;
        __syncthreads();
        tsum[t] += add;
        __syncthreads();
    }
    if (t < NB) lofs[t] = tsum[t] - v;
    if (t == SBS - 1) lofs[NB] = tsum[SBS - 1];
    __syncthreads();
    if (t < NB) {
        lbase[t] = v ? atomicAdd(&cursor[t], v) : 0;
        hist[t] = 0;
    }
    for (int q = t; q < CHUNK / 16; q += SBS) {
        int pos = q * 16;
        int lo = 0, hi = NB;
        while (hi - lo > 1) {
            int mid = (lo + hi) >> 1;
            if (lofs[mid] <= pos) lo = mid; else hi = mid;
        }
        flr[q] = (unsigned short)lo;
    }
    __syncthreads();
    #pragma unroll
    for (int j = 0; j < CHUNK / SBS; ++j) {
        int i = t + j * SBS;
        if (i < count) {
            int e = base + i;
            int r = rloc[j];
            int b = r >> 7;
            int pos = lofs[b] + atomicAdd(&hist[b], 1);
            srt[pos] = make_uint2(((unsigned)(r & 127) << 17) | (unsigned)col[e],
                                  __float_as_uint(w[e]));
        }
    }
    __syncthreads();
    for (int i = t; i < count; i += SBS) {
        uint2 vv = srt[i];
        int b = flr[i >> 4];
        while (lofs[b + 1] <= i) ++b;
        rec[lbase[b] + (i - lofs[b])] = vv;
    }
}

// ================= stage 2: compact-base scan over bucket counts =================
__global__ void scan_nb(const int* __restrict__ cursor, int* __restrict__ bbase) {
    __shared__ int s[1024];
    const int t = threadIdx.x;
    int v = (t < NB) ? (cursor[t] - t * CAP) : 0;
    s[t] = v;
    __syncthreads();
    for (int off = 1; off < 1024; off <<= 1) {
        int add = (t >= off) ? s[t - off] : 0;
        __syncthreads();
        s[t] += add;
        __syncthreads();
    }
    if (t < NB) bbase[t] = s[t] - v;
    if (t == NB - 1) bbase[NB] = s[t];
}

// ====== stage 3: per-bucket counting sort by (row_local, col_tile) -> CSR ======
// rec2[i] = (w_f16_no_sign:15) << 17 | col:17; each row's edges col-tile-ordered.
__global__ __launch_bounds__(512) void bucket_sort(
        const int* __restrict__ cursor, const int* __restrict__ bbase,
        const uint2* __restrict__ rec, unsigned* __restrict__ rec2,
        int* __restrict__ row_ptr, int n_nodes) {
    __shared__ unsigned srt[CAP];     // 20 KB
    __shared__ int hist[NKEYS];       // 8 KB
    __shared__ int lofs[NKEYS];       // 8 KB
    __shared__ int tsum[512];         // 2 KB
    const int t = threadIdx.x;
    const int b = blockIdx.x;
    const int sbase = b * CAP;
    const int cnt = cursor[b] - sbase;
    const int gbase = bbase[b];

    for (int i = t; i < NKEYS; i += 512) hist[i] = 0;
    __syncthreads();
    for (int i = t; i < cnt; i += 512) {
        unsigned rx = rec[sbase + i].x;
        int key = (rx >> 17) * CTILES + ((rx & 0x1FFFFu) >> 13);
        atomicAdd(&hist[key], 1);
    }
    __syncthreads();
    int vals[4];
    int s0 = 0;
    const int k4 = t * 4;
    #pragma unroll
    for (int j = 0; j < 4; ++j) { vals[j] = hist[k4 + j]; s0 += vals[j]; }
    tsum[t] = s0;
    __syncthreads();
    for (int off = 1; off < 512; off <<= 1) {
        int add = (t >= off) ? tsum[t - off] : 0;
        __syncthreads();
        tsum[t] += add;
        __syncthreads();
    }
    {
        int run = tsum[t] - s0;
        #pragma unroll
        for (int j = 0; j < 4; ++j) { lofs[k4 + j] = run; run += vals[j]; }
    }
    __syncthreads();
    if (t < RPB) {
        int gr = b * RPB + t;
        if (gr <= n_nodes) row_ptr[gr] = gbase + lofs[t * CTILES];
    }
    for (int i = t; i < NKEYS; i += 512) hist[i] = lofs[i];
    __syncthreads();
    for (int i = t; i < cnt; i += 512) {
        uint2 v = rec[sbase + i];
        int key = (v.x >> 17) * CTILES + ((v.x & 0x1FFFFu) >> 13);
        int pos = atomicAdd(&hist[key], 1);
        float wf = __uint_as_float(v.y);
        __half hw = __float2half_rn(wf);
        unsigned wb = ((unsigned)*reinterpret_cast<unsigned short*>(&hw)) & 0x7FFFu;
        srt[pos] = (wb << 17) | (v.x & 0x1FFFFu);
    }
    __syncthreads();
    for (int i = t; i < cnt; i += 512)
        rec2[gbase + i] = srt[i];
}

#define CONSUME(G, P) do {                                          \
    unsigned wu_ = (P) >> 17; wu_ |= wu_ << 16;                     \
    __half2 w2_ = u2h2(wu_);                                        \
    a0 = __hfma2(w2_, u2h2((G).x), a0);                             \
    a1 = __hfma2(w2_, u2h2((G).y), a1);                             \
    a2 = __hfma2(w2_, u2h2((G).z), a2);                             \
    a3 = __hfma2(w2_, u2h2((G).w), a3); } while (0)

#define EDGE1 do {                                                  \
    unsigned p0_ = rec2[i];                                         \
    uint4 g0_ = h4[(size_t)(p0_ & 0x1FFFF) * 4 + fl];               \
    CONSUME(g0_, p0_); } while (0)

// ====== fused SPMM: act = ELU(A.h + b); then project @Wn -> f16, or pool. ======
// 4 lanes/node (uint4 = 8 f16 feats each), 64 nodes/block.
// Col-sweep PACING: edges are col-tile-sorted per row; process them in PHASES
// fractions so all resident waves gather from a sliding ~1-2.5 MB L2 window
// instead of thrashing the full 6.4 MB h table (cuts L2-miss/EA bytes).
__global__ __launch_bounds__(256) void spmm_fused(
        const int* __restrict__ rp, const unsigned* __restrict__ rec2,
        const unsigned short* __restrict__ h_in, const float* __restrict__ bias,
        const float* __restrict__ Wn,          // 32x32 or nullptr (last layer)
        unsigned short* __restrict__ h_out,    // f16 out if Wn != nullptr
        const int* __restrict__ seg,           // used if Wn == nullptr
        float* __restrict__ G,                 // pooled out if Wn == nullptr
        int n_nodes) {
    __shared__ float Ws[32 * 32];
    __shared__ float vt[SPB][33];
    const int t = threadIdx.x;
    if (Wn) for (int i = t; i < 1024; i += 256) Ws[i] = Wn[i];
    const int fl = t & 3;
    const int nl = t >> 2;
    const int node = blockIdx.x * SPB + nl;
    const bool valid = node < n_nodes;
    const int s = valid ? rp[node] : 0;
    const int e = valid ? rp[node + 1] : 0;
    const int d = e - s;
    const uint4* h4 = (const uint4*)h_in;     // row = 4 uint4 (32 f16)
    __half2 a0 = u2h2(0), a1 = u2h2(0), a2 = u2h2(0), a3 = u2h2(0);
    int i = s;
    // paced col-sweep: phase ph covers the first ph/PHASES of this row's
    // (col-sorted) edges; the ph-loop is wave-uniform so all lanes advance
    // through col-space together.
    #pragma unroll
    for (int ph = 1; ph <= PHASES; ++ph) {
        const int end = s + (d * ph) / PHASES;   // end(PHASES) == e exactly
        // 4-deep gather batch for MLP
        for (; i + 4 <= end; i += 4) {
            unsigned p0 = rec2[i];
            unsigned p1 = rec2[i + 1];
            unsigned p2 = rec2[i + 2];
            unsigned p3 = rec2[i + 3];
            uint4 g0 = h4[(size_t)(p0 & 0x1FFFF) * 4 + fl];
            uint4 g1 = h4[(size_t)(p1 & 0x1FFFF) * 4 + fl];
            uint4 g2 = h4[(size_t)(p2 & 0x1FFFF) * 4 + fl];
            uint4 g3 = h4[(size_t)(p3 & 0x1FFFF) * 4 + fl];
            CONSUME(g0, p0); CONSUME(g1, p1);
            CONSUME(g2, p2); CONSUME(g3, p3);
        }
        for (; i < end; ++i) EDGE1;
    }

    // bias + ELU in fp32
    float acc[8];
    acc[0] = __low2float(a0); acc[1] = __high2float(a0);
    acc[2] = __low2float(a1); acc[3] = __high2float(a1);
    acc[4] = __low2float(a2); acc[5] = __high2float(a2);
    acc[6] = __low2float(a3); acc[7] = __high2float(a3);
    float4 bv0 = ((const float4*)bias)[fl * 2];
    float4 bv1 = ((const float4*)bias)[fl * 2 + 1];
    acc[0] += bv0.x; acc[1] += bv0.y; acc[2] += bv0.z; acc[3] += bv0.w;
    acc[4] += bv1.x; acc[5] += bv1.y; acc[6] += bv1.z; acc[7] += bv1.w;
    #pragma unroll
    for (int j = 0; j < 8; ++j)
        acc[j] = acc[j] > 0.f ? acc[j] : (expf(acc[j]) - 1.f);
    // stage act in LDS
    {
        float* vr = &vt[nl][fl * 8];
        #pragma unroll
        for (int j = 0; j < 8; ++j) vr[j] = acc[j];
    }
    __syncthreads();

    if (Wn) {
        // project @ Wn, emit f16
        const float4* Ws4 = (const float4*)Ws;
        const float* vrow = vt[nl];
        float o[8] = {0.f, 0.f, 0.f, 0.f, 0.f, 0.f, 0.f, 0.f};
        #pragma unroll 8
        for (int k = 0; k < 32; ++k) {
            float vk = vrow[k];
            float4 w0 = Ws4[k * 8 + fl * 2];
            float4 w1 = Ws4[k * 8 + fl * 2 + 1];
            o[0] += vk * w0.x; o[1] += vk * w0.y; o[2] += vk * w0.z; o[3] += vk * w0.w;
            o[4] += vk * w1.x; o[5] += vk * w1.y; o[6] += vk * w1.z; o[7] += vk * w1.w;
        }
        if (valid) {
            __half2 q0 = __floats2half2_rn(o[0], o[1]);
            __half2 q1 = __floats2half2_rn(o[2], o[3]);
            __half2 q2 = __floats2half2_rn(o[4], o[5]);
            __half2 q3 = __floats2half2_rn(o[6], o[7]);
            uint4 ob = make_uint4(*reinterpret_cast<unsigned*>(&q0),
                                  *reinterpret_cast<unsigned*>(&q1),
                                  *reinterpret_cast<unsigned*>(&q2),
                                  *reinterpret_cast<unsigned*>(&q3));
            ((uint4*)h_out)[(size_t)node * 4 + fl] = ob;
        }
    } else {
        // pool: 32 feat lanes x 8 subs, run-accumulate sorted seg over 8 nodes each
        const int f = t & 31;
        const int sub = t >> 5;
        float run = 0.f;
        int cur = -1;
        #pragma unroll
        for (int q = 0; q < 8; ++q) {
            int nloc = sub * 8 + q;
            int node2 = blockIdx.x * SPB + nloc;
            if (node2 >= n_nodes) break;
            int sg = seg[node2];
            if (sg != cur) {
                if (cur >= 0) atomicAdd(&G[(size_t)cur * 32 + f], run);
                cur = sg;
                run = 0.f;
            }
            run += vt[nloc][f];
        }
        if (cur >= 0) atomicAdd(&G[(size_t)cur * 32 + f], run);
    }
}

// ================= MLP head =================
__global__ void head_mlp(const float* __restrict__ g,
                         const float* __restrict__ Wd1, const float* __restrict__ bd1,
                         const float* __restrict__ Wd2, const float* __restrict__ bd2,
                         const float* __restrict__ Wd3, const float* __restrict__ bd3,
                         float* __restrict__ out) {
    __shared__ float gr[32];
    __shared__ float s1[64];
    __shared__ float s2[32];
    const int gid = blockIdx.x;
    const int t = threadIdx.x;
    if (t < 32) gr[t] = g[(size_t)gid * 32 + t];
    __syncthreads();
    float a = bd1[t];
    for (int k = 0; k < 32; ++k) a += gr[k] * Wd1[k * 64 + t];
    s1[t] = fmaxf(a, 0.f);
    __syncthreads();
    if (t < 32) {
        float a2 = bd2[t];
        for (int k = 0; k < 64; ++k) a2 += s1[k] * Wd2[k * 32 + t];
        s2[t] = fmaxf(a2, 0.f);
    }
    __syncthreads();
    if (t == 0) {
        float a3 = bd3[0];
        for (int k = 0; k < 32; ++k) a3 += s2[k] * Wd3[k];
        out[gid] = 1.f / (1.f + expf(-a3));
    }
}

extern "C" void kernel_launch(void* const* d_in, const int* in_sizes, int n_in,
                              void* d_out, int out_size, void* d_ws, size_t ws_size,
                              hipStream_t stream) {
    const float* x   = (const float*)d_in[0];
    const int*   ei  = (const int*)d_in[1];
    const float* ew  = (const float*)d_in[2];
    const int*   seg = (const int*)d_in[3];
    const float* W1  = (const float*)d_in[4];
    const float* b1  = (const float*)d_in[5];
    const float* W2  = (const float*)d_in[6];
    const float* b2  = (const float*)d_in[7];
    const float* W3  = (const float*)d_in[8];
    const float* b3  = (const float*)d_in[9];
    const float* Wd1 = (const float*)d_in[10];
    const float* bd1 = (const float*)d_in[11];
    const float* Wd2 = (const float*)d_in[12];
    const float* bd2 = (const float*)d_in[13];
    const float* Wd3 = (const float*)d_in[14];
    const float* bd3 = (const float*)d_in[15];
    float* out = (float*)d_out;

    const int* rowp = ei;
    const int* colp = ei + N_EDGES;

    const size_t NF  = (size_t)N_NODES * F_HID;
    const size_t REC_BYTES = (size_t)NB * CAP * sizeof(uint2);  // 32.03 MB

    // region A: rec (32 MB) during build; hA (6.4) + hB (6.4) f16 overlay after
    char*  wsb     = (char*)d_ws;
    uint2* rec     = (uint2*)wsb;
    unsigned short* hA = (unsigned short*)wsb;                  // f16 [N,32]
    unsigned short* hB = (unsigned short*)(wsb + NF * 2);       // f16 [N,32]
    unsigned* rec2 = (unsigned*)(wsb + REC_BYTES);              // [E] 4 B records
    int*   cursor  = (int*)(rec2 + N_EDGES);                    // [NB]
    int*   bbase   = cursor + NB;                               // [NB+1]
    int*   row_ptr = bbase + NB + 1;                            // [N+1]
    float* G       = (float*)(row_ptr + N_NODES + 1);           // [512,32]

    const int gemm_grid = (N_NODES + 31) / 32;        // 3125
    const int spmm_grid = (N_NODES + SPB - 1) / SPB;  // 1563

    // ---- CSR build (once per call) ----
    init_cursor<<<(NB + 255) / 256, 256, 0, stream>>>(cursor);
    bucket_scatter<<<NCHUNK, SBS, 0, stream>>>(rowp, colp, ew, cursor, rec, N_EDGES);
    scan_nb<<<1, 1024, 0, stream>>>(cursor, bbase);
    bucket_sort<<<NB, 512, 0, stream>>>(cursor, bbase, rec, rec2, row_ptr, N_NODES);
    hipMemsetAsync(G, 0, (size_t)N_GRAPHS * F_HID * sizeof(float), stream);

    // ---- layer 1: project x@W1 -> hA; fused spmm(+b1,ELU) @W2 -> hB ----
    gemm128x32<<<gemm_grid, 256, 0, stream>>>(x, W1, hA, N_NODES);
    spmm_fused<<<spmm_grid, 256, 0, stream>>>(row_ptr, rec2, hA, b1, W2, hB, nullptr, nullptr, N_NODES);

    // ---- layer 2: fused spmm(+b2,ELU) @W3 -> hA ----
    spmm_fused<<<spmm_grid, 256, 0, stream>>>(row_ptr, rec2, hB, b2, W3, hA, nullptr, nullptr, N_NODES);

    // ---- layer 3: fused spmm(+b3,ELU) + pool -> G ----
    spmm_fused<<<spmm_grid, 256, 0, stream>>>(row_ptr, rec2, hA, b3, nullptr, nullptr, seg, G, N_NODES);

    // ---- head ----
    head_mlp<<<N_GRAPHS, 64, 0, stream>>>(G, Wd1, bd1, Wd2, bd2, Wd3, bd3, out);
}